// Round 1
// baseline (816.783 us; speedup 1.0000x reference)
//
#include <hip/hip_runtime.h>

#define HID 64

// ---------------- CSR build ----------------

__global__ void k_hist(const int* __restrict__ dst, int E, int* __restrict__ deg) {
    int i = blockIdx.x * blockDim.x + threadIdx.x;
    int stride = gridDim.x * blockDim.x;
    for (; i < E; i += stride) atomicAdd(&deg[dst[i]], 1);
}

__global__ void k_scan1(const int* __restrict__ deg, int N,
                        int* __restrict__ row_start, int* __restrict__ bsum,
                        float* __restrict__ dis) {
    __shared__ int sh[1024];
    int i = blockIdx.x * 1024 + threadIdx.x;
    int v = (i < N) ? deg[i] : 0;
    if (i < N) dis[i] = rsqrtf((float)(v + 1));  // deg incl. self loop, always >0
    sh[threadIdx.x] = v;
    __syncthreads();
    for (int ofs = 1; ofs < 1024; ofs <<= 1) {
        int t = (threadIdx.x >= (unsigned)ofs) ? sh[threadIdx.x - ofs] : 0;
        __syncthreads();
        sh[threadIdx.x] += t;
        __syncthreads();
    }
    if (i < N) row_start[i] = sh[threadIdx.x] - v;  // exclusive scan (block-local)
    if (threadIdx.x == 1023) bsum[blockIdx.x] = sh[1023];
}

__global__ void k_scan2(int* __restrict__ bsum, int nb) {
    if (blockIdx.x == 0 && threadIdx.x == 0) {
        int run = 0;
        for (int i = 0; i < nb; i++) { int v = bsum[i]; bsum[i] = run; run += v; }
    }
}

__global__ void k_scan3(int* __restrict__ row_start, int* __restrict__ cursor,
                        const int* __restrict__ bsum, int N, int E) {
    int i = blockIdx.x * 1024 + threadIdx.x;
    if (i < N) {
        int r = row_start[i] + bsum[blockIdx.x];
        row_start[i] = r;
        cursor[i] = r;
    }
    if (i == 0) row_start[N] = E;
}

__global__ void k_fill(const int* __restrict__ src, const int* __restrict__ dst,
                       int E, int* __restrict__ cursor, int* __restrict__ col) {
    int i = blockIdx.x * blockDim.x + threadIdx.x;
    int stride = gridDim.x * blockDim.x;
    for (; i < E; i += stride) {
        int p = atomicAdd(&cursor[dst[i]], 1);
        col[p] = src[i];
    }
}

// ---------------- per-layer compute ----------------

// out[n,f] = (X[n,:] @ W[:,f]) * dis[n]   ; W is [64,64] row-major
__global__ __launch_bounds__(256) void k_gemm_scale(
        const float* __restrict__ X, const float* __restrict__ W,
        const float* __restrict__ dis, float* __restrict__ out, int N) {
    __shared__ float Wsh[64 * 64];
    __shared__ float xsh[4][64];
    for (int i = threadIdx.x; i < 64 * 64; i += blockDim.x) Wsh[i] = W[i];
    __syncthreads();
    const int wave = threadIdx.x >> 6;
    const int lane = threadIdx.x & 63;
    float wcol[64];
#pragma unroll
    for (int k = 0; k < 64; k++) wcol[k] = Wsh[k * 64 + lane];

    const int nwaves = gridDim.x * 4;
    for (int node = blockIdx.x * 4 + wave; node < N; node += nwaves) {
        xsh[wave][lane] = X[(size_t)node * 64 + lane];
        asm volatile("s_waitcnt lgkmcnt(0)" ::: "memory");  // cross-lane LDS RAW within wave
        float acc = 0.f;
#pragma unroll
        for (int k = 0; k < 64; k += 4) {
            float4 xv = *(const float4*)&xsh[wave][k];  // broadcast read
            acc += xv.x * wcol[k]     + xv.y * wcol[k + 1]
                 + xv.z * wcol[k + 2] + xv.w * wcol[k + 3];
        }
        out[(size_t)node * 64 + lane] = acc * dis[node];
    }
}

// h[n,f] = relu( dis[n] * ( hw[n,f] + sum_{e in CSR[n]} hw[col[e],f] ) + b[f] )
__global__ __launch_bounds__(256) void k_gather(
        const float* __restrict__ hw, const int* __restrict__ row_start,
        const int* __restrict__ col, const float* __restrict__ dis,
        const float* __restrict__ bias, float* __restrict__ out, int N) {
    const int wave = threadIdx.x >> 6;
    const int lane = threadIdx.x & 63;
    const float b = bias[lane];
    const int nwaves = gridDim.x * 4;
    for (int node = blockIdx.x * 4 + wave; node < N; node += nwaves) {
        float acc = hw[(size_t)node * 64 + lane];  // self loop
        int s = row_start[node];
        int e = row_start[node + 1];
        for (int j = s; j < e; j++) {
            int c = col[j];  // wave-uniform broadcast load
            acc += hw[(size_t)c * 64 + lane];
        }
        out[(size_t)node * 64 + lane] = fmaxf(acc * dis[node] + b, 0.f);
    }
}

// ---------------- pool + MLP ----------------

__global__ void k_pool(const float* __restrict__ h, const int* __restrict__ batch,
                       int N, float* __restrict__ pooled) {
    const int g = blockIdx.x;
    const int lane = threadIdx.x;  // 64 threads
    // lower_bound(batch, v): first idx with batch[idx] >= v  (batch is sorted)
    int lo = 0, hi = N;
    while (lo < hi) { int mid = (lo + hi) >> 1; if (batch[mid] < g) lo = mid + 1; else hi = mid; }
    int s = lo;
    lo = 0; hi = N;
    while (lo < hi) { int mid = (lo + hi) >> 1; if (batch[mid] < g + 1) lo = mid + 1; else hi = mid; }
    int e = lo;
    float acc = 0.f;
    for (int i = s; i < e; i++) acc += h[(size_t)i * 64 + lane];
    float cnt = (float)(e - s);
    pooled[(size_t)g * 64 + lane] = acc / fmaxf(cnt, 1.f);
}

__global__ void k_mlp(const float* __restrict__ pooled, const float* __restrict__ Wc1,
                      const float* __restrict__ bc1, const float* __restrict__ Wc2,
                      const float* __restrict__ bc2, float* __restrict__ out) {
    __shared__ float sh[64];
    const int g = blockIdx.x;
    const int t = threadIdx.x;  // 64 threads = 1 wave
    sh[t] = pooled[(size_t)g * 64 + t];
    __syncthreads();
    float part = 0.f;
    if (t < 32) {
        float z = bc1[t];
#pragma unroll
        for (int f = 0; f < 64; f++) z += sh[f] * Wc1[f * 32 + t];
        z = fmaxf(z, 0.f);
        part = z * Wc2[t];
    }
    for (int ofs = 32; ofs > 0; ofs >>= 1) part += __shfl_down(part, ofs);
    if (t == 0) out[g] = part + bc2[0];
}

// ---------------- launch ----------------

extern "C" void kernel_launch(void* const* d_in, const int* in_sizes, int n_in,
                              void* d_out, int out_size, void* d_ws, size_t ws_size,
                              hipStream_t stream) {
    const float* x     = (const float*)d_in[0];
    const int*   ei    = (const int*)d_in[1];
    const int*   batch = (const int*)d_in[2];
    const float* W1 = (const float*)d_in[3];  const float* b1 = (const float*)d_in[4];
    const float* W2 = (const float*)d_in[5];  const float* b2 = (const float*)d_in[6];
    const float* W3 = (const float*)d_in[7];  const float* b3 = (const float*)d_in[8];
    const float* Wc1 = (const float*)d_in[9];  const float* bc1 = (const float*)d_in[10];
    const float* Wc2 = (const float*)d_in[11]; const float* bc2 = (const float*)d_in[12];
    float* out = (float*)d_out;

    const int N = in_sizes[0] / 64;   // 100000
    const int E = in_sizes[1] / 2;    // 1600000
    const int G = out_size;           // 1024
    const int* src = ei;
    const int* dst = ei + E;

    char* w = (char*)d_ws;
    auto alloc = [&](size_t bytes) -> void* {
        void* p = (void*)w;
        w += (bytes + 255) & ~(size_t)255;
        return p;
    };
    int*   deg       = (int*)alloc((size_t)N * 4);
    float* dis       = (float*)alloc((size_t)N * 4);
    int*   row_start = (int*)alloc((size_t)(N + 1) * 4);
    int*   cursor    = (int*)alloc((size_t)N * 4);
    int*   bsum      = (int*)alloc(1024);
    int*   col       = (int*)alloc((size_t)E * 4);
    float* bufA      = (float*)alloc((size_t)N * 64 * 4);
    float* bufB      = (float*)alloc((size_t)N * 64 * 4);
    float* pooled    = (float*)alloc((size_t)G * 64 * 4);
    (void)ws_size; (void)n_in;

    hipMemsetAsync(deg, 0, (size_t)N * 4, stream);
    k_hist<<<1024, 256, 0, stream>>>(dst, E, deg);
    const int nb = (N + 1023) / 1024;
    k_scan1<<<nb, 1024, 0, stream>>>(deg, N, row_start, bsum, dis);
    k_scan2<<<1, 64, 0, stream>>>(bsum, nb);
    k_scan3<<<nb, 1024, 0, stream>>>(row_start, cursor, bsum, N, E);
    k_fill<<<1024, 256, 0, stream>>>(src, dst, E, cursor, col);

    // layer 1
    k_gemm_scale<<<1024, 256, 0, stream>>>(x, W1, dis, bufA, N);
    k_gather<<<4096, 256, 0, stream>>>(bufA, row_start, col, dis, b1, bufB, N);
    // layer 2
    k_gemm_scale<<<1024, 256, 0, stream>>>(bufB, W2, dis, bufA, N);
    k_gather<<<4096, 256, 0, stream>>>(bufA, row_start, col, dis, b2, bufB, N);
    // layer 3
    k_gemm_scale<<<1024, 256, 0, stream>>>(bufB, W3, dis, bufA, N);
    k_gather<<<4096, 256, 0, stream>>>(bufA, row_start, col, dis, b3, bufB, N);

    k_pool<<<G, 64, 0, stream>>>(bufB, batch, N, pooled);
    k_mlp<<<G, 64, 0, stream>>>(pooled, Wc1, bc1, Wc2, bc2, out);
}

// Round 2
// 553.640 us; speedup vs baseline: 1.4753x; 1.4753x over previous
//
#include <hip/hip_runtime.h>

#define HID 64

// ---------------- CSR build ----------------

__global__ void k_hist(const int* __restrict__ dst, int E, int* __restrict__ deg) {
    int i = blockIdx.x * blockDim.x + threadIdx.x;
    int stride = gridDim.x * blockDim.x;
    for (; i < E; i += stride) atomicAdd(&deg[dst[i]], 1);
}

__global__ void k_scan1(const int* __restrict__ deg, int N,
                        int* __restrict__ row_start, int* __restrict__ bsum,
                        float* __restrict__ dis) {
    __shared__ int sh[1024];
    int i = blockIdx.x * 1024 + threadIdx.x;
    int v = (i < N) ? deg[i] : 0;
    if (i < N) dis[i] = rsqrtf((float)(v + 1));  // deg incl. self loop, always >0
    sh[threadIdx.x] = v;
    __syncthreads();
    for (int ofs = 1; ofs < 1024; ofs <<= 1) {
        int t = (threadIdx.x >= (unsigned)ofs) ? sh[threadIdx.x - ofs] : 0;
        __syncthreads();
        sh[threadIdx.x] += t;
        __syncthreads();
    }
    if (i < N) row_start[i] = sh[threadIdx.x] - v;  // exclusive scan (block-local)
    if (threadIdx.x == 1023) bsum[blockIdx.x] = sh[1023];
}

__global__ void k_scan2(int* __restrict__ bsum, int nb) {
    if (blockIdx.x == 0 && threadIdx.x == 0) {
        int run = 0;
        for (int i = 0; i < nb; i++) { int v = bsum[i]; bsum[i] = run; run += v; }
    }
}

__global__ void k_scan3(int* __restrict__ row_start, int* __restrict__ cursor,
                        const int* __restrict__ bsum, int N, int E) {
    int i = blockIdx.x * 1024 + threadIdx.x;
    if (i < N) {
        int r = row_start[i] + bsum[blockIdx.x];
        row_start[i] = r;
        cursor[i] = r;
    }
    if (i == 0) row_start[N] = E;
}

__global__ void k_fill(const int* __restrict__ src, const int* __restrict__ dst,
                       int E, int* __restrict__ cursor, int* __restrict__ col) {
    int i = blockIdx.x * blockDim.x + threadIdx.x;
    int stride = gridDim.x * blockDim.x;
    for (; i < E; i += stride) {
        int p = atomicAdd(&cursor[dst[i]], 1);
        col[p] = src[i];
    }
}

// ---------------- per-layer compute ----------------

// out[n,f] = (X[n,:] @ W[:,f]) * dis[n]   ; W is [64,64] row-major
__global__ __launch_bounds__(256) void k_gemm_scale(
        const float* __restrict__ X, const float* __restrict__ W,
        const float* __restrict__ dis, float* __restrict__ out, int N) {
    __shared__ float Wsh[64 * 64];
    __shared__ float xsh[4][64];
    for (int i = threadIdx.x; i < 64 * 64; i += blockDim.x) Wsh[i] = W[i];
    __syncthreads();
    const int wave = threadIdx.x >> 6;
    const int lane = threadIdx.x & 63;
    float wcol[64];
#pragma unroll
    for (int k = 0; k < 64; k++) wcol[k] = Wsh[k * 64 + lane];

    const int nwaves = gridDim.x * 4;
    for (int node = blockIdx.x * 4 + wave; node < N; node += nwaves) {
        xsh[wave][lane] = X[(size_t)node * 64 + lane];
        asm volatile("s_waitcnt lgkmcnt(0)" ::: "memory");  // cross-lane LDS RAW within wave
        float acc = 0.f;
#pragma unroll
        for (int k = 0; k < 64; k += 4) {
            float4 xv = *(const float4*)&xsh[wave][k];  // broadcast read
            acc += xv.x * wcol[k]     + xv.y * wcol[k + 1]
                 + xv.z * wcol[k + 2] + xv.w * wcol[k + 3];
        }
        out[(size_t)node * 64 + lane] = acc * dis[node];
    }
}

// h[n,f] = relu( dis[n] * ( hw[n,f] + sum_{e in CSR[n]} hw[col[e],f] ) + b[f] )
// Wave layout: quarter q = lane>>4 handles edge j+q; lane t = lane&15 owns
// features 4t..4t+3 as a float4 (16 B/lane, 1 KB/wave per load instruction).
// Unrolled x2 -> >=2 KB in flight per wave.
__global__ __launch_bounds__(256) void k_gather(
        const float* __restrict__ hw, const int* __restrict__ row_start,
        const int* __restrict__ col, const float* __restrict__ dis,
        const float* __restrict__ bias, float* __restrict__ out, int N) {
    const int wave = threadIdx.x >> 6;
    const int lane = threadIdx.x & 63;
    const int q = lane >> 4;
    const int t = lane & 15;
    const float4 b4 = *(const float4*)&bias[4 * t];
    const int nwaves = gridDim.x * 4;
    for (int node = blockIdx.x * 4 + wave; node < N; node += nwaves) {
        int s = row_start[node];
        int e = row_start[node + 1];
        float4 acc;
        if (q == 0) {
            acc = *(const float4*)&hw[(size_t)node * 64 + 4 * t];  // self loop
        } else {
            acc.x = 0.f; acc.y = 0.f; acc.z = 0.f; acc.w = 0.f;
        }
        int j = s + q;
        for (; j + 4 < e; j += 8) {
            int c0 = col[j];
            int c1 = col[j + 4];
            const float4 v0 = *(const float4*)&hw[(size_t)c0 * 64 + 4 * t];
            const float4 v1 = *(const float4*)&hw[(size_t)c1 * 64 + 4 * t];
            acc.x += v0.x; acc.y += v0.y; acc.z += v0.z; acc.w += v0.w;
            acc.x += v1.x; acc.y += v1.y; acc.z += v1.z; acc.w += v1.w;
        }
        if (j < e) {
            int c = col[j];
            const float4 v = *(const float4*)&hw[(size_t)c * 64 + 4 * t];
            acc.x += v.x; acc.y += v.y; acc.z += v.z; acc.w += v.w;
        }
        // reduce across the 4 quarters (lanes l, l^16, l^32)
        acc.x += __shfl_xor(acc.x, 16); acc.y += __shfl_xor(acc.y, 16);
        acc.z += __shfl_xor(acc.z, 16); acc.w += __shfl_xor(acc.w, 16);
        acc.x += __shfl_xor(acc.x, 32); acc.y += __shfl_xor(acc.y, 32);
        acc.z += __shfl_xor(acc.z, 32); acc.w += __shfl_xor(acc.w, 32);
        if (q == 0) {
            float d = dis[node];
            float4 r;
            r.x = fmaxf(acc.x * d + b4.x, 0.f);
            r.y = fmaxf(acc.y * d + b4.y, 0.f);
            r.z = fmaxf(acc.z * d + b4.z, 0.f);
            r.w = fmaxf(acc.w * d + b4.w, 0.f);
            *(float4*)&out[(size_t)node * 64 + 4 * t] = r;
        }
    }
}

// ---------------- pool + MLP ----------------

__global__ void k_pool(const float* __restrict__ h, const int* __restrict__ batch,
                       int N, float* __restrict__ pooled) {
    const int g = blockIdx.x;
    const int lane = threadIdx.x;  // 64 threads
    int lo = 0, hi = N;
    while (lo < hi) { int mid = (lo + hi) >> 1; if (batch[mid] < g) lo = mid + 1; else hi = mid; }
    int s = lo;
    lo = 0; hi = N;
    while (lo < hi) { int mid = (lo + hi) >> 1; if (batch[mid] < g + 1) lo = mid + 1; else hi = mid; }
    int e = lo;
    float acc = 0.f;
    for (int i = s; i < e; i++) acc += h[(size_t)i * 64 + lane];
    float cnt = (float)(e - s);
    pooled[(size_t)g * 64 + lane] = acc / fmaxf(cnt, 1.f);
}

__global__ void k_mlp(const float* __restrict__ pooled, const float* __restrict__ Wc1,
                      const float* __restrict__ bc1, const float* __restrict__ Wc2,
                      const float* __restrict__ bc2, float* __restrict__ out) {
    __shared__ float sh[64];
    const int g = blockIdx.x;
    const int t = threadIdx.x;  // 64 threads = 1 wave
    sh[t] = pooled[(size_t)g * 64 + t];
    __syncthreads();
    float part = 0.f;
    if (t < 32) {
        float z = bc1[t];
#pragma unroll
        for (int f = 0; f < 64; f++) z += sh[f] * Wc1[f * 32 + t];
        z = fmaxf(z, 0.f);
        part = z * Wc2[t];
    }
    for (int ofs = 32; ofs > 0; ofs >>= 1) part += __shfl_down(part, ofs);
    if (t == 0) out[g] = part + bc2[0];
}

// ---------------- launch ----------------

extern "C" void kernel_launch(void* const* d_in, const int* in_sizes, int n_in,
                              void* d_out, int out_size, void* d_ws, size_t ws_size,
                              hipStream_t stream) {
    const float* x     = (const float*)d_in[0];
    const int*   ei    = (const int*)d_in[1];
    const int*   batch = (const int*)d_in[2];
    const float* W1 = (const float*)d_in[3];  const float* b1 = (const float*)d_in[4];
    const float* W2 = (const float*)d_in[5];  const float* b2 = (const float*)d_in[6];
    const float* W3 = (const float*)d_in[7];  const float* b3 = (const float*)d_in[8];
    const float* Wc1 = (const float*)d_in[9];  const float* bc1 = (const float*)d_in[10];
    const float* Wc2 = (const float*)d_in[11]; const float* bc2 = (const float*)d_in[12];
    float* out = (float*)d_out;

    const int N = in_sizes[0] / 64;   // 100000
    const int E = in_sizes[1] / 2;    // 1600000
    const int G = out_size;           // 1024
    const int* src = ei;
    const int* dst = ei + E;

    char* w = (char*)d_ws;
    auto alloc = [&](size_t bytes) -> void* {
        void* p = (void*)w;
        w += (bytes + 255) & ~(size_t)255;
        return p;
    };
    int*   deg       = (int*)alloc((size_t)N * 4);
    float* dis       = (float*)alloc((size_t)N * 4);
    int*   row_start = (int*)alloc((size_t)(N + 1) * 4);
    int*   cursor    = (int*)alloc((size_t)N * 4);
    int*   bsum      = (int*)alloc(1024);
    int*   col       = (int*)alloc((size_t)E * 4);
    float* bufA      = (float*)alloc((size_t)N * 64 * 4);
    float* bufB      = (float*)alloc((size_t)N * 64 * 4);
    float* pooled    = (float*)alloc((size_t)G * 64 * 4);
    (void)ws_size; (void)n_in;

    hipMemsetAsync(deg, 0, (size_t)N * 4, stream);
    k_hist<<<1024, 256, 0, stream>>>(dst, E, deg);
    const int nb = (N + 1023) / 1024;
    k_scan1<<<nb, 1024, 0, stream>>>(deg, N, row_start, bsum, dis);
    k_scan2<<<1, 64, 0, stream>>>(bsum, nb);
    k_scan3<<<nb, 1024, 0, stream>>>(row_start, cursor, bsum, N, E);
    k_fill<<<1024, 256, 0, stream>>>(src, dst, E, cursor, col);

    // layer 1
    k_gemm_scale<<<1024, 256, 0, stream>>>(x, W1, dis, bufA, N);
    k_gather<<<4096, 256, 0, stream>>>(bufA, row_start, col, dis, b1, bufB, N);
    // layer 2
    k_gemm_scale<<<1024, 256, 0, stream>>>(bufB, W2, dis, bufA, N);
    k_gather<<<4096, 256, 0, stream>>>(bufA, row_start, col, dis, b2, bufB, N);
    // layer 3
    k_gemm_scale<<<1024, 256, 0, stream>>>(bufB, W3, dis, bufA, N);
    k_gather<<<4096, 256, 0, stream>>>(bufA, row_start, col, dis, b3, bufB, N);

    k_pool<<<G, 64, 0, stream>>>(bufB, batch, N, pooled);
    k_mlp<<<G, 64, 0, stream>>>(pooled, Wc1, bc1, Wc2, bc2, out);
}

// Round 3
// 505.458 us; speedup vs baseline: 1.6159x; 1.0953x over previous
//
#include <hip/hip_runtime.h>

#define HID 64
#define NBUF 800   // padded per-set bucket stride (>= NB)
#define PAD 4      // ints per counter slot (16 B) to spread atomic lines

// ---------------- CSR build: 8-way bucketed counting sort ----------------

__global__ void k_bhist8(const int* __restrict__ dst, int E, int* __restrict__ bcnt) {
    const int x = blockIdx.x & 7;
    int i = blockIdx.x * blockDim.x + threadIdx.x;
    int stride = gridDim.x * blockDim.x;
    for (; i < E; i += stride) {
        int b = dst[i] >> 7;
        atomicAdd(&bcnt[(x * NBUF + b) * PAD], 1);
    }
}

// exclusive scan over (bucket-major, then x) of the 8-way histogram
__global__ void k_bscan(const int* __restrict__ bcnt, int* __restrict__ bcur,
                        int* __restrict__ bucket_base, int NB, int E,
                        int* __restrict__ row_start, int N) {
    __shared__ int sums[1024];
    const int t = threadIdx.x;
    const int total = NB * 8;
    const int per = (total + 1023) / 1024;  // <= 8 for N <= 131072
    int base = t * per;
    int vals[8];
    int s = 0;
    for (int k = 0; k < per; k++) {
        int f = base + k;
        int v = 0;
        if (f < total) {
            int b = f >> 3, x = f & 7;
            v = bcnt[(x * NBUF + b) * PAD];
        }
        vals[k] = s;  // local exclusive prefix
        s += v;
    }
    sums[t] = s;
    __syncthreads();
    for (int ofs = 1; ofs < 1024; ofs <<= 1) {
        int v = (t >= ofs) ? sums[t - ofs] : 0;
        __syncthreads();
        sums[t] += v;
        __syncthreads();
    }
    int carry = (t > 0) ? sums[t - 1] : 0;
    for (int k = 0; k < per; k++) {
        int f = base + k;
        if (f < total) {
            int b = f >> 3, x = f & 7;
            int ex = carry + vals[k];
            bcur[(x * NBUF + b) * PAD] = ex;
            if (x == 0) bucket_base[b] = ex;
        }
    }
    if (t == 0) { bucket_base[NB] = E; row_start[N] = E; }
}

__global__ void k_bfill8(const int* __restrict__ src, const int* __restrict__ dst,
                         int E, int* __restrict__ bcur, int* __restrict__ tmp) {
    const int x = blockIdx.x & 7;  // same mapping as k_bhist8
    int i = blockIdx.x * blockDim.x + threadIdx.x;
    int stride = gridDim.x * blockDim.x;
    for (; i < E; i += stride) {
        int d = dst[i];
        int b = d >> 7;
        int p = atomicAdd(&bcur[(x * NBUF + b) * PAD], 1);
        tmp[p] = src[i] | ((d & 127) << 17);
    }
}

// one block per bucket: local histogram -> dis/row_start, then local scatter of col
__global__ __launch_bounds__(256) void k_bpass2(
        const int* __restrict__ tmp, const int* __restrict__ bucket_base,
        int* __restrict__ col, int* __restrict__ row_start,
        float* __restrict__ dis, int N) {
    __shared__ int lcnt[128];
    __shared__ int lofs[128];
    const int b = blockIdx.x;
    const int t = threadIdx.x;
    const int s = bucket_base[b];
    const int e = bucket_base[b + 1];
    if (t < 128) lcnt[t] = 0;
    __syncthreads();
    for (int i = s + t; i < e; i += 256) {
        int d = (tmp[i] >> 17) & 127;
        atomicAdd(&lcnt[d], 1);
    }
    __syncthreads();
    if (t < 128) lofs[t] = lcnt[t];
    __syncthreads();
    for (int ofs = 1; ofs < 128; ofs <<= 1) {
        int v = 0;
        if (t < 128 && t >= ofs) v = lofs[t - ofs];
        __syncthreads();
        if (t < 128) lofs[t] += v;
        __syncthreads();
    }
    if (t < 128) {
        int node = (b << 7) + t;
        int ex = lofs[t] - lcnt[t];   // exclusive prefix
        if (node < N) {
            row_start[node] = s + ex;
            dis[node] = rsqrtf((float)(lcnt[t] + 1));  // + self loop
        }
        lcnt[t] = s + ex;  // reuse as global cursor
    }
    __syncthreads();
    for (int i = s + t; i < e; i += 256) {
        int v = tmp[i];
        int d = (v >> 17) & 127;
        int p = atomicAdd(&lcnt[d], 1);
        col[p] = v & 0x1FFFF;
    }
}

// ---------------- per-layer compute ----------------

// out[n,f] = (X[n,:] @ W[:,f]) * dis[n]   ; W is [64,64] row-major
__global__ __launch_bounds__(256) void k_gemm_scale(
        const float* __restrict__ X, const float* __restrict__ W,
        const float* __restrict__ dis, float* __restrict__ out, int N) {
    __shared__ float Wsh[64 * 64];
    __shared__ float xsh[4][64];
    for (int i = threadIdx.x; i < 64 * 64; i += blockDim.x) Wsh[i] = W[i];
    __syncthreads();
    const int wave = threadIdx.x >> 6;
    const int lane = threadIdx.x & 63;
    float wcol[64];
#pragma unroll
    for (int k = 0; k < 64; k++) wcol[k] = Wsh[k * 64 + lane];

    const int nwaves = gridDim.x * 4;
    for (int node = blockIdx.x * 4 + wave; node < N; node += nwaves) {
        xsh[wave][lane] = X[(size_t)node * 64 + lane];
        asm volatile("s_waitcnt lgkmcnt(0)" ::: "memory");
        float acc = 0.f;
#pragma unroll
        for (int k = 0; k < 64; k += 4) {
            float4 xv = *(const float4*)&xsh[wave][k];  // broadcast read
            acc += xv.x * wcol[k]     + xv.y * wcol[k + 1]
                 + xv.z * wcol[k + 2] + xv.w * wcol[k + 3];
        }
        out[(size_t)node * 64 + lane] = acc * dis[node];
    }
}

// h[n,f] = relu( dis[n] * ( hw[n,f] + sum_{e in CSR[n]} hw[col[e],f] ) + b[f] )
// quarter q = lane>>4 handles edge j+q; t = lane&15 owns features 4t..4t+3.
__global__ __launch_bounds__(256) void k_gather(
        const float* __restrict__ hw, const int* __restrict__ row_start,
        const int* __restrict__ col, const float* __restrict__ dis,
        const float* __restrict__ bias, float* __restrict__ out, int N) {
    const int wave = threadIdx.x >> 6;
    const int lane = threadIdx.x & 63;
    const int q = lane >> 4;
    const int t = lane & 15;
    const float4 b4 = *(const float4*)&bias[4 * t];
    const int nwaves = gridDim.x * 4;
    for (int node = blockIdx.x * 4 + wave; node < N; node += nwaves) {
        int s = row_start[node];
        int e = row_start[node + 1];
        float4 acc;
        if (q == 0) {
            acc = *(const float4*)&hw[(size_t)node * 64 + 4 * t];  // self loop
        } else {
            acc.x = 0.f; acc.y = 0.f; acc.z = 0.f; acc.w = 0.f;
        }
        int j = s + q;
        for (; j + 4 < e; j += 8) {
            int c0 = col[j];
            int c1 = col[j + 4];
            const float4 v0 = *(const float4*)&hw[(size_t)c0 * 64 + 4 * t];
            const float4 v1 = *(const float4*)&hw[(size_t)c1 * 64 + 4 * t];
            acc.x += v0.x; acc.y += v0.y; acc.z += v0.z; acc.w += v0.w;
            acc.x += v1.x; acc.y += v1.y; acc.z += v1.z; acc.w += v1.w;
        }
        if (j < e) {
            int c = col[j];
            const float4 v = *(const float4*)&hw[(size_t)c * 64 + 4 * t];
            acc.x += v.x; acc.y += v.y; acc.z += v.z; acc.w += v.w;
        }
        acc.x += __shfl_xor(acc.x, 16); acc.y += __shfl_xor(acc.y, 16);
        acc.z += __shfl_xor(acc.z, 16); acc.w += __shfl_xor(acc.w, 16);
        acc.x += __shfl_xor(acc.x, 32); acc.y += __shfl_xor(acc.y, 32);
        acc.z += __shfl_xor(acc.z, 32); acc.w += __shfl_xor(acc.w, 32);
        if (q == 0) {
            float d = dis[node];
            float4 r;
            r.x = fmaxf(acc.x * d + b4.x, 0.f);
            r.y = fmaxf(acc.y * d + b4.y, 0.f);
            r.z = fmaxf(acc.z * d + b4.z, 0.f);
            r.w = fmaxf(acc.w * d + b4.w, 0.f);
            *(float4*)&out[(size_t)node * 64 + 4 * t] = r;
        }
    }
}

// ---------------- pool + MLP ----------------

__global__ void k_pool(const float* __restrict__ h, const int* __restrict__ batch,
                       int N, float* __restrict__ pooled) {
    const int g = blockIdx.x;
    const int lane = threadIdx.x;  // 64 threads
    int lo = 0, hi = N;
    while (lo < hi) { int mid = (lo + hi) >> 1; if (batch[mid] < g) lo = mid + 1; else hi = mid; }
    int s = lo;
    lo = 0; hi = N;
    while (lo < hi) { int mid = (lo + hi) >> 1; if (batch[mid] < g + 1) lo = mid + 1; else hi = mid; }
    int e = lo;
    float acc = 0.f;
    for (int i = s; i < e; i++) acc += h[(size_t)i * 64 + lane];
    float cnt = (float)(e - s);
    pooled[(size_t)g * 64 + lane] = acc / fmaxf(cnt, 1.f);
}

__global__ void k_mlp(const float* __restrict__ pooled, const float* __restrict__ Wc1,
                      const float* __restrict__ bc1, const float* __restrict__ Wc2,
                      const float* __restrict__ bc2, float* __restrict__ out) {
    __shared__ float sh[64];
    const int g = blockIdx.x;
    const int t = threadIdx.x;  // 64 threads = 1 wave
    sh[t] = pooled[(size_t)g * 64 + t];
    __syncthreads();
    float part = 0.f;
    if (t < 32) {
        float z = bc1[t];
#pragma unroll
        for (int f = 0; f < 64; f++) z += sh[f] * Wc1[f * 32 + t];
        z = fmaxf(z, 0.f);
        part = z * Wc2[t];
    }
    for (int ofs = 32; ofs > 0; ofs >>= 1) part += __shfl_down(part, ofs);
    if (t == 0) out[g] = part + bc2[0];
}

// ---------------- launch ----------------

extern "C" void kernel_launch(void* const* d_in, const int* in_sizes, int n_in,
                              void* d_out, int out_size, void* d_ws, size_t ws_size,
                              hipStream_t stream) {
    const float* x     = (const float*)d_in[0];
    const int*   ei    = (const int*)d_in[1];
    const int*   batch = (const int*)d_in[2];
    const float* W1 = (const float*)d_in[3];  const float* b1 = (const float*)d_in[4];
    const float* W2 = (const float*)d_in[5];  const float* b2 = (const float*)d_in[6];
    const float* W3 = (const float*)d_in[7];  const float* b3 = (const float*)d_in[8];
    const float* Wc1 = (const float*)d_in[9];  const float* bc1 = (const float*)d_in[10];
    const float* Wc2 = (const float*)d_in[11]; const float* bc2 = (const float*)d_in[12];
    float* out = (float*)d_out;

    const int N = in_sizes[0] / 64;   // 100000
    const int E = in_sizes[1] / 2;    // 1600000
    const int G = out_size;           // 1024
    const int* src = ei;
    const int* dst = ei + E;
    const int NB = (N + 127) >> 7;    // 782 buckets

    char* w = (char*)d_ws;
    auto alloc = [&](size_t bytes) -> void* {
        void* p = (void*)w;
        w += (bytes + 255) & ~(size_t)255;
        return p;
    };
    float* dis         = (float*)alloc((size_t)N * 4);
    int*   row_start   = (int*)alloc((size_t)(N + 1) * 4);
    int*   col         = (int*)alloc((size_t)E * 4);
    int*   bcnt        = (int*)alloc((size_t)8 * NBUF * PAD * 4);
    int*   bcur        = (int*)alloc((size_t)8 * NBUF * PAD * 4);
    int*   bucket_base = (int*)alloc((size_t)(NB + 1) * 4);
    float* bufA        = (float*)alloc((size_t)N * 64 * 4);
    float* bufB        = (float*)alloc((size_t)N * 64 * 4);
    float* pooled      = (float*)alloc((size_t)G * 64 * 4);
    int*   tmp         = (int*)bufA;  // alias: CSR build finishes before layer 1
    (void)ws_size; (void)n_in;

    hipMemsetAsync(bcnt, 0, (size_t)8 * NBUF * PAD * 4, stream);
    k_bhist8<<<1024, 256, 0, stream>>>(dst, E, bcnt);
    k_bscan<<<1, 1024, 0, stream>>>(bcnt, bcur, bucket_base, NB, E, row_start, N);
    k_bfill8<<<1024, 256, 0, stream>>>(src, dst, E, bcur, tmp);
    k_bpass2<<<NB, 256, 0, stream>>>(tmp, bucket_base, col, row_start, dis, N);

    // layer 1
    k_gemm_scale<<<1024, 256, 0, stream>>>(x, W1, dis, bufA, N);
    k_gather<<<4096, 256, 0, stream>>>(bufA, row_start, col, dis, b1, bufB, N);
    // layer 2
    k_gemm_scale<<<1024, 256, 0, stream>>>(bufB, W2, dis, bufA, N);
    k_gather<<<4096, 256, 0, stream>>>(bufA, row_start, col, dis, b2, bufB, N);
    // layer 3
    k_gemm_scale<<<1024, 256, 0, stream>>>(bufB, W3, dis, bufA, N);
    k_gather<<<4096, 256, 0, stream>>>(bufA, row_start, col, dis, b3, bufB, N);

    k_pool<<<G, 64, 0, stream>>>(bufB, batch, N, pooled);
    k_mlp<<<G, 64, 0, stream>>>(pooled, Wc1, bc1, Wc2, bc2, out);
}